// Round 7
// baseline (209.808 us; speedup 1.0000x reference)
//
#include <hip/hip_runtime.h>

// B=8, H=8, L=2048, D=64, num_delays=16
static constexpr int LSEQ = 2048;
static constexpr int NB   = 8;
static constexpr int NH   = 8;
static constexpr int ND   = 64;
static constexpr int NDEL = 16;

// ws layout (8.4 MiB total — proven-safe size):
//   P     : float2[64 part][8 b][2048]  at 0        (8 MiB) partial spectra, digit-rev order
//           (after reduce_S, part 0 holds the reduced spectrum S in-place)
//   w     : float [8][16]               at 8388608
//   delay : int   [8][16]               at 8389120
static constexpr size_t WS_P_OFF     = 0;
static constexpr size_t WS_W_OFF     = 8388608;
static constexpr size_t WS_DELAY_OFF = 8389120;

// LDS bank swizzle on float2 index: fold bits 4..6 into bits 1..3.
__device__ __forceinline__ int SWZ(int x) { return x ^ (((x >> 4) & 7) << 1); }

// digit-reversed position of frequency f (radices 8,8,8,4 DIF) and inverse
__device__ __forceinline__ int pof(int f) {
    return ((f & 7) << 8) | (((f >> 3) & 7) << 5) | (((f >> 6) & 7) << 2) | (f >> 9);
}
__device__ __forceinline__ int fofp(int p) {
    return (p >> 8) | (((p >> 5) & 7) << 3) | (((p >> 2) & 7) << 6) | ((p & 3) << 9);
}

#define CMUL(ar, ai, br, bi) make_float2((ar)*(br) - (ai)*(bi), (ar)*(bi) + (ai)*(br))

// 8-pt DIF DFT in regs; x[0..7] in, X[0..7] (natural freq order) out.
__device__ __forceinline__ void dft8(const float2 x[8], float2 X[8]) {
    const float RH = 0.70710678118654752440f;
    float2 a0 = make_float2(x[0].x + x[4].x, x[0].y + x[4].y);
    float2 a1 = make_float2(x[1].x + x[5].x, x[1].y + x[5].y);
    float2 a2 = make_float2(x[2].x + x[6].x, x[2].y + x[6].y);
    float2 a3 = make_float2(x[3].x + x[7].x, x[3].y + x[7].y);
    float2 b0 = make_float2(x[0].x - x[4].x, x[0].y - x[4].y);
    float  t1r = x[1].x - x[5].x, t1i = x[1].y - x[5].y;
    float2 b1 = make_float2(RH * (t1r + t1i), RH * (t1i - t1r));       // * w8^1
    float  t2r = x[2].x - x[6].x, t2i = x[2].y - x[6].y;
    float2 b2 = make_float2(t2i, -t2r);                                // * -i
    float  t3r = x[3].x - x[7].x, t3i = x[3].y - x[7].y;
    float2 b3 = make_float2(RH * (t3i - t3r), -RH * (t3r + t3i));      // * w8^3
    float2 c0 = make_float2(a0.x + a2.x, a0.y + a2.y);
    float2 d0 = make_float2(a0.x - a2.x, a0.y - a2.y);
    float2 c1 = make_float2(a1.x + a3.x, a1.y + a3.y);
    float2 d1 = make_float2(a1.y - a3.y, -(a1.x - a3.x));              // * -i
    X[0] = make_float2(c0.x + c1.x, c0.y + c1.y);
    X[4] = make_float2(c0.x - c1.x, c0.y - c1.y);
    X[2] = make_float2(d0.x + d1.x, d0.y + d1.y);
    X[6] = make_float2(d0.x - d1.x, d0.y - d1.y);
    float2 e0 = make_float2(b0.x + b2.x, b0.y + b2.y);
    float2 f0 = make_float2(b0.x - b2.x, b0.y - b2.y);
    float2 e1 = make_float2(b1.x + b3.x, b1.y + b3.y);
    float2 f1 = make_float2(b1.y - b3.y, -(b1.x - b3.x));              // * -i
    X[1] = make_float2(e0.x + e1.x, e0.y + e1.y);
    X[5] = make_float2(e0.x - e1.x, e0.y - e1.y);
    X[3] = make_float2(f0.x + f1.x, f0.y + f1.y);
    X[7] = make_float2(f0.x - f1.x, f0.y - f1.y);
}

// 4-pt DFT: X[m] = sum_j x[j] (-i)^{jm}
__device__ __forceinline__ void dft4(const float2 x[4], float2 X[4]) {
    float2 s0 = make_float2(x[0].x + x[2].x, x[0].y + x[2].y);
    float2 s1 = make_float2(x[1].x + x[3].x, x[1].y + x[3].y);
    float2 d0 = make_float2(x[0].x - x[2].x, x[0].y - x[2].y);
    float2 d1 = make_float2(x[1].y - x[3].y, -(x[1].x - x[3].x));      // * -i
    X[0] = make_float2(s0.x + s1.x, s0.y + s1.y);
    X[2] = make_float2(s0.x - s1.x, s0.y - s1.y);
    X[1] = make_float2(d0.x + d1.x, d0.y + d1.y);
    X[3] = make_float2(d0.x - d1.x, d0.y - d1.y);
}

// in-place radix-8 stage with twiddle chain W on LDS plane zp
__device__ __forceinline__ void stageR8(float2* zp, const int adr[8], const float2 W[7]) {
    float2 X[8], Y[8];
    #pragma unroll
    for (int j = 0; j < 8; ++j) X[j] = zp[adr[j]];
    dft8(X, Y);
    #pragma unroll
    for (int m = 1; m < 8; ++m) Y[m] = CMUL(Y[m].x, Y[m].y, W[m-1].x, W[m-1].y);
    #pragma unroll
    for (int m = 0; m < 8; ++m) zp[adr[m]] = Y[m];
}

// final twiddle-free stage: two radix-4 on 8 consecutive slots, in-place.
__device__ __forceinline__ void stageD4(float2* zp, const int adr[8]) {
    float2 xin[8], X[8];
    #pragma unroll
    for (int j = 0; j < 8; ++j) xin[j] = zp[adr[j]];
    dft4(&xin[0], &X[0]);
    dft4(&xin[4], &X[4]);
    #pragma unroll
    for (int m = 0; m < 8; ++m) zp[adr[m]] = X[m];
}

// ---------------------------------------------------------------------------
// Kernel A: block = (b,h,grp of 8 d-channels). Mixed-radix 8*8*8*4 DIF FFT.
// FOUR channels in flight per sync phase (4 x 16 KiB LDS planes = 64 KiB):
// ~11 barriers/block (vs 21), 4 independent chains per inter-barrier section.
// Product P[f]=Q conj(K) via P[2048-f]=conj(P[f]); owned slots cc in {0,1,4,5},
// all operands re-read from LDS (keeps VGPR pressure bounded). No atomics.
// ---------------------------------------------------------------------------
__global__ __launch_bounds__(256, 2) void fft_corr(const float* __restrict__ q,
                                                   const float* __restrict__ k,
                                                   float2* __restrict__ P) {
    __shared__ float2 zP[4][LSEQ];          // 64 KiB (swizzled)
    const int t   = threadIdx.x;
    const int bi  = blockIdx.x;             // 512 = 8 xcd * 8 bh * 8 grp
    const int xcd = bi & 7;
    const int sl  = bi >> 3;
    const int bh  = xcd * 8 + (sl >> 3);
    const int grp = sl & 7;
    const int b   = bh >> 3;
    const int h   = bh & 7;
    const size_t base = (size_t)bh * LSEQ * ND + (size_t)(grp * 8);

    // twiddle power chains (per thread, shared by all channels)
    float2 WA[7], WB[7], WC[7];
    {
        float sn, cs;
        __sincosf(-6.28318530717958647692f * (float)t / 2048.f, &sn, &cs);
        WA[0] = make_float2(cs, sn);
        __sincosf(-6.28318530717958647692f * (float)(t & 31) / 256.f, &sn, &cs);
        WB[0] = make_float2(cs, sn);
        __sincosf(-6.28318530717958647692f * (float)(t & 3) / 32.f, &sn, &cs);
        WC[0] = make_float2(cs, sn);
        #pragma unroll
        for (int m = 1; m < 7; ++m) {
            WA[m] = CMUL(WA[m-1].x, WA[m-1].y, WA[0].x, WA[0].y);
            WB[m] = CMUL(WB[m-1].x, WB[m-1].y, WB[0].x, WB[0].y);
            WC[m] = CMUL(WC[m-1].x, WC[m-1].y, WC[0].x, WC[0].y);
        }
    }

    // owned product slots: cc in {0,1,4,5} -> f in [0,1024)
    int fS[4], pmS[4];
    #pragma unroll
    for (int s = 0; s < 4; ++s) {
        const int cc = (s < 2) ? s : s + 2;           // {0,1,4,5}
        const int f  = fofp(8 * t + cc);
        const int m  = (2048 - f) & 2047;
        fS[s]  = f;
        pmS[s] = SWZ(pof(m));
    }
    float aFr[4] = {0, 0, 0, 0}, aFi[4] = {0, 0, 0, 0};
    float aS = 0.f;                      // f=1024 special (thread 0, slot p=2)

    const int sbB   = (t >> 5) * 256 + (t & 31);
    const int baseC = (t >> 2) * 32 + (t & 3);
    int adrB[8], adrC[8], adrD[8];
    #pragma unroll
    for (int n = 0; n < 8; ++n) {
        adrB[n] = SWZ(sbB + 32 * n);
        adrC[n] = SWZ(baseC + 4 * n);
        adrD[n] = SWZ(8 * t + n);
    }

    #pragma unroll 1
    for (int half = 0; half < 2; ++half) {
        float4 qa[8], ka[8];
        #pragma unroll
        for (int j = 0; j < 8; ++j) {
            const size_t r = base + (size_t)(t + 256 * j) * ND + half * 4;
            qa[j] = *(const float4*)(q + r);
            ka[j] = *(const float4*)(k + r);
        }
        __syncthreads();             // planes free (prev half's product reads done)

        // stage A: radix-8 on rows t+256j (from staging regs), scatter to bands
        #pragma unroll
        for (int c = 0; c < 4; ++c) {
            float2 X[8], Y[8];
            #pragma unroll
            for (int j = 0; j < 8; ++j)
                X[j] = make_float2((&qa[j].x)[c], (&ka[j].x)[c]);
            dft8(X, Y);
            #pragma unroll
            for (int m = 1; m < 8; ++m) Y[m] = CMUL(Y[m].x, Y[m].y, WA[m-1].x, WA[m-1].y);
            #pragma unroll
            for (int m = 0; m < 8; ++m) zP[c][SWZ(m * 256 + t)] = Y[m];
        }
        __syncthreads();

        #pragma unroll
        for (int c = 0; c < 4; ++c) stageR8(zP[c], adrB, WB);
        __syncthreads();

        #pragma unroll
        for (int c = 0; c < 4; ++c) stageR8(zP[c], adrC, WC);
        __syncthreads();

        #pragma unroll
        for (int c = 0; c < 4; ++c) stageD4(zP[c], adrD);
        __syncthreads();

        // product: P[f] += Q[f] conj(K[f]) for 4 owned slots, 4 channels
        #pragma unroll
        for (int s = 0; s < 4; ++s) {
            const int cc = (s < 2) ? s : s + 2;   // {0,1,4,5}
            const int own = adrD[cc];
            #pragma unroll
            for (int c = 0; c < 4; ++c) {
                const float2 Zf = zP[c][own];
                const float2 Zm = zP[c][pmS[s]];
                const float qr = 0.5f * (Zf.x + Zm.x), qi = 0.5f * (Zf.y - Zm.y);
                const float kr = 0.5f * (Zf.y + Zm.y), ki = 0.5f * (Zm.x - Zf.x);
                aFr[s] += qr * kr + qi * ki;
                aFi[s] += qi * kr - qr * ki;
            }
        }
        if (t == 0) {
            #pragma unroll
            for (int c = 0; c < 4; ++c) {
                const float2 Z = zP[c][adrD[2]];   // slot 2 = pof(1024)
                aS += Z.x * Z.y;
            }
        }
    }

    // stores: direct slots contiguous; mirrors conj-scattered (disjoint slots)
    const int part = h * 8 + grp;
    float2* Pp = P + (size_t)part * (NB * 2048) + (size_t)b * 2048;
    *(float4*)&Pp[8 * t]     = make_float4(aFr[0], aFi[0], aFr[1], aFi[1]);
    *(float4*)&Pp[8 * t + 4] = make_float4(aFr[2], aFi[2], aFr[3], aFi[3]);
    #pragma unroll
    for (int s = 0; s < 4; ++s) {
        const int m = (2048 - fS[s]) & 2047;
        if (m != fS[s]) Pp[pof(m)] = make_float2(aFr[s], -aFi[s]);
    }
    if (t == 0) Pp[pof(1024)] = make_float2(aS, 0.f);
}

// ---------------------------------------------------------------------------
// Reduce 64 partials IN-PLACE into part 0 (thread g owns column g — race-free).
// ---------------------------------------------------------------------------
__global__ __launch_bounds__(256) void reduce_S(float2* __restrict__ P) {
    const int g = blockIdx.x * 256 + threadIdx.x;    // 0..16383 = b*2048+pos
    float ax = 0.f, ay = 0.f;
    #pragma unroll 8
    for (int part = 0; part < 64; ++part) {
        const float2 v = P[(size_t)part * (NB * 2048) + g];
        ax += v.x; ay += v.y;
    }
    P[g] = make_float2(ax, ay);
}

// ---------------------------------------------------------------------------
// Kernel B: block per batch, 256 threads. IFFT via conj trick on the verified
// mixed-radix pipeline; stage D leaves each thread's 8 mean-corr values in
// REGISTERS (value + tau index). Top-16: per-wave in-register shuffle-argmax
// (zero barriers) -> 64 candidates -> wave-0 64-lane merge. Ties -> smaller tau.
// ---------------------------------------------------------------------------
__global__ __launch_bounds__(256) void ifft_topk(const float2* __restrict__ S,
                                                 float* __restrict__ wout,
                                                 int* __restrict__ dout) {
    __shared__ float2 zz[LSEQ];          // 16 KiB work
    __shared__ float  candV[64];
    __shared__ int    candI[64];
    __shared__ float  topv[NDEL];
    __shared__ int    topi[NDEL];
    const int b = blockIdx.x, t = threadIdx.x;
    const int lane = t & 63, wv = t >> 6;

    float2 WA[7], WB[7], WC[7];
    {
        float sn, cs;
        __sincosf(-6.28318530717958647692f * (float)t / 2048.f, &sn, &cs);
        WA[0] = make_float2(cs, sn);
        __sincosf(-6.28318530717958647692f * (float)(t & 31) / 256.f, &sn, &cs);
        WB[0] = make_float2(cs, sn);
        __sincosf(-6.28318530717958647692f * (float)(t & 3) / 32.f, &sn, &cs);
        WC[0] = make_float2(cs, sn);
        #pragma unroll
        for (int m = 1; m < 7; ++m) {
            WA[m] = CMUL(WA[m-1].x, WA[m-1].y, WA[0].x, WA[0].y);
            WB[m] = CMUL(WB[m-1].x, WB[m-1].y, WB[0].x, WB[0].y);
            WC[m] = CMUL(WC[m-1].x, WC[m-1].y, WC[0].x, WC[0].y);
        }
    }
    const int sbB   = (t >> 5) * 256 + (t & 31);
    const int baseC = (t >> 2) * 32 + (t & 3);
    int adrB[8], adrC[8], adrD[8];
    #pragma unroll
    for (int n = 0; n < 8; ++n) {
        adrB[n] = SWZ(sbB + 32 * n);
        adrC[n] = SWZ(baseC + 4 * n);
        adrD[n] = SWZ(8 * t + n);
    }

    // coalesced load of S (digit-rev slots) into zz (non-swizzled slots)
    #pragma unroll
    for (int j = 0; j < 8; ++j) zz[t + 256 * j] = S[b * 2048 + t + 256 * j];
    __syncthreads();

    // gather stage-A operands: x[f] = conj(S[f]) at slot pof(f), f = t+256j
    float2 X[8], Y[8];
    #pragma unroll
    for (int j = 0; j < 8; ++j) {
        const float2 s = zz[pof(t + 256 * j)];
        X[j] = make_float2(s.x, -s.y);
    }
    __syncthreads();                     // all gathers done before scatter

    dft8(X, Y);
    #pragma unroll
    for (int m = 1; m < 8; ++m) Y[m] = CMUL(Y[m].x, Y[m].y, WA[m-1].x, WA[m-1].y);
    #pragma unroll
    for (int m = 0; m < 8; ++m) zz[SWZ(m * 256 + t)] = Y[m];
    __syncthreads();

    stageR8(zz, adrB, WB);
    __syncthreads();
    stageR8(zz, adrC, WC);
    __syncthreads();

    // stage D in regs only; values + tau indices stay in registers
    float vreg[8]; int ireg[8];
    {
        float2 xin[8];
        #pragma unroll
        for (int j = 0; j < 8; ++j) xin[j] = zz[adrD[j]];
        dft4(&xin[0], &X[0]);
        dft4(&xin[4], &X[4]);
        const float scale = 1.0f / ((float)LSEQ * (float)(NH * ND));
        #pragma unroll
        for (int cc = 0; cc < 8; ++cc) {
            vreg[cc] = X[cc].x * scale;
            ireg[cc] = fofp(8 * t + cc);
        }
    }

    // per-wave top-16 over 512 register values (wave-synchronous, no barriers)
    for (int it = 0; it < NDEL; ++it) {
        float bv = -3e38f; int bix = 0x7fffffff, bcc = -1;
        #pragma unroll
        for (int cc = 0; cc < 8; ++cc) {
            if (vreg[cc] > bv || (vreg[cc] == bv && ireg[cc] < bix)) {
                bv = vreg[cc]; bix = ireg[cc]; bcc = cc;
            }
        }
        float fv = bv; int fix = bix;
        #pragma unroll
        for (int off = 32; off; off >>= 1) {
            const float ov = __shfl_xor(fv, off);
            const int   oi = __shfl_xor(fix, off);
            if (ov > fv || (ov == fv && oi < fix)) { fv = ov; fix = oi; }
        }
        if (fix == bix && bcc >= 0) vreg[bcc] = -3e38f;   // unique tau -> winner only
        if (lane == 0) { candV[wv * NDEL + it] = fv; candI[wv * NDEL + it] = fix; }
    }
    __syncthreads();

    // wave 0: merge 64 candidates (one per lane) with 16x 64-lane argmax
    if (wv == 0) {
        float val = candV[lane]; int idx = candI[lane];
        for (int it = 0; it < NDEL; ++it) {
            float fv = val; int fix = idx;
            #pragma unroll
            for (int off = 32; off; off >>= 1) {
                const float ov = __shfl_xor(fv, off);
                const int   oi = __shfl_xor(fix, off);
                if (ov > fv || (ov == fv && oi < fix)) { fv = ov; fix = oi; }
            }
            if (idx == fix) val = -3e38f;                 // unique tau -> winner lane
            if (lane == 0) { topv[it] = fv; topi[it] = fix; }
        }
        if (lane == 0) {
            const float m = topv[0];
            float e[NDEL], sum = 0.f;
            for (int i = 0; i < NDEL; ++i) { e[i] = __expf(topv[i] - m); sum += e[i]; }
            const float inv = 1.0f / sum;
            for (int i = 0; i < NDEL; ++i) {
                wout[b * NDEL + i] = e[i] * inv;
                dout[b * NDEL + i] = topi[i];
            }
        }
    }
}

// ---------------------------------------------------------------------------
// Kernel C: out[b,h,t,d] = sum_k w[b,k] * v[b,h,(t+delay[b,k]) & 2047, d]
// XCD swizzle: 128 t-tiles of one (b,h) share an XCD (v slice L2-resident).
// ---------------------------------------------------------------------------
__global__ __launch_bounds__(256) void gather_out(const float* __restrict__ v,
                                                  const float* __restrict__ w,
                                                  const int* __restrict__ delay,
                                                  float* __restrict__ out) {
    const int bi  = blockIdx.x;          // 8192 = 64 bh * 128 tiles
    const int xcd = bi & 7;
    const int s   = bi >> 3;
    const int bh  = xcd * 8 + (s >> 7);
    const int bt  = s & 127;
    const int b   = bh >> 3;
    const int tid = threadIdx.x;

    __shared__ float sw_[NDEL];
    __shared__ int   sd_[NDEL];
    if (tid < NDEL) {
        sw_[tid] = w[b * NDEL + tid];
        sd_[tid] = delay[b * NDEL + tid];
    }
    __syncthreads();

    const float* vb = v + (size_t)bh * LSEQ * ND;
    float*       ob = out + (size_t)bh * LSEQ * ND;

    const int row = tid >> 4;
    const int col = (tid & 15) * 4;
    const int t   = bt * 16 + row;

    float4 acc = make_float4(0.f, 0.f, 0.f, 0.f);
    #pragma unroll
    for (int kk = 0; kk < NDEL; ++kk) {
        const int r = (t + sd_[kk]) & (LSEQ - 1);
        const float4 vv = *(const float4*)(vb + (size_t)r * ND + col);
        const float wv = sw_[kk];
        acc.x += wv * vv.x; acc.y += wv * vv.y;
        acc.z += wv * vv.z; acc.w += wv * vv.w;
    }
    *(float4*)(ob + (size_t)t * ND + col) = acc;
}

// ---------------------------------------------------------------------------
extern "C" void kernel_launch(void* const* d_in, const int* in_sizes, int n_in,
                              void* d_out, int out_size, void* d_ws, size_t ws_size,
                              hipStream_t stream) {
    const float* q = (const float*)d_in[0];
    const float* k = (const float*)d_in[1];
    const float* v = (const float*)d_in[2];
    float* out = (float*)d_out;

    float2* P     = (float2*)((char*)d_ws + WS_P_OFF);
    float*  w     = (float*)((char*)d_ws + WS_W_OFF);
    int*    delay = (int*)((char*)d_ws + WS_DELAY_OFF);

    fft_corr<<<dim3(512), dim3(256), 0, stream>>>(q, k, P);
    reduce_S<<<dim3(64), dim3(256), 0, stream>>>(P);
    ifft_topk<<<dim3(NB), dim3(256), 0, stream>>>(P, w, delay);  // S = P[part 0]
    gather_out<<<dim3(NB * NH * 128), dim3(256), 0, stream>>>(v, w, delay, out);
}